// Round 1
// baseline (1544.369 us; speedup 1.0000x reference)
//
#include <hip/hip_runtime.h>
#include <stdint.h>

typedef __attribute__((ext_vector_type(8))) short bf16x8_t;
typedef __attribute__((ext_vector_type(4))) float f32x4_t;
typedef unsigned short u16;

#define NB 4
#define CH 1024
#define CI_ 512
#define NSP 12544
#define NK 3136

__device__ __forceinline__ float bf2f(u16 u) {
  union { unsigned int i; float f; } v; v.i = ((unsigned int)u) << 16; return v.f;
}
__device__ __forceinline__ u16 f2bf(float f) {
  unsigned int x = __float_as_uint(f);
  x += 0x7fffu + ((x >> 16) & 1u);
  return (u16)(x >> 16);
}

#define MFMA16(a,b,c) __builtin_amdgcn_mfma_f32_16x16x32_bf16((a),(b),(c),0,0,0)

#define GLDS16(g, l) __builtin_amdgcn_global_load_lds( \
    (const __attribute__((address_space(1))) void*)(g), \
    (__attribute__((address_space(3))) void*)(l), 16, 0, 0)

// ---------------- weight cast fp32 -> bf16 (4 x 524288) ----------------
__global__ __launch_bounds__(256) void k_cast_w(
    const float* __restrict__ tw, const float* __restrict__ pw,
    const float* __restrict__ gw, const float* __restrict__ ww,
    u16* __restrict__ out)
{
  int i = blockIdx.x * 256 + threadIdx.x;
  if (i >= 4 * 524288) return;
  int seg = i >> 19, off = i & 524287;
  const float* s = (seg == 0) ? tw : (seg == 1) ? pw : (seg == 2) ? gw : ww;
  out[i] = f2bf(s[off]);
}

// ---------------- x (B,C,N) f32 -> xT (B,N,C) bf16 ----------------
__global__ __launch_bounds__(256) void k_transpose(
    const float* __restrict__ x, u16* __restrict__ xT)
{
  __shared__ float tile[64][65];
  int b = blockIdx.z, cb = blockIdx.y * 64, nb = blockIdx.x * 64;
  const float* xb = x + ((long long)b * CH + cb) * NSP + nb;
  int tr = threadIdx.x >> 6, tc = threadIdx.x & 63;
#pragma unroll
  for (int i = 0; i < 16; ++i) {
    int r = tr + i * 4;
    tile[r][tc] = xb[(long long)r * NSP + tc];
  }
  __syncthreads();
  u16* yb = xT + ((long long)b * NSP + nb) * CH + cb;
#pragma unroll
  for (int i = 0; i < 16; ++i) {
    int r = tr + i * 4;
    yb[(long long)r * CH + tc] = f2bf(tile[tc][r]);
  }
}

// ---------------- maxpool (1,2,2): xT -> xpT (B,Nk,C) bf16 ----------------
__global__ __launch_bounds__(256) void k_pool(
    const u16* __restrict__ xT, u16* __restrict__ xpT)
{
  int tid = blockIdx.x * 256 + threadIdx.x;
  if (tid >= NB * NK * 128) return;
  int c8 = tid & 127;
  int g = tid >> 7;
  int nk = g % NK, b = g / NK;
  int t = nk / 196, r2 = nk % 196, hp = r2 / 14, wp = r2 % 14;
  int n00 = t * 784 + hp * 2 * 28 + wp * 2;
  const u16* p = xT + ((long long)b * NSP + n00) * CH + c8 * 8;
  bf16x8_t v0 = *(const bf16x8_t*)p;
  bf16x8_t v1 = *(const bf16x8_t*)(p + CH);
  bf16x8_t v2 = *(const bf16x8_t*)(p + 28 * CH);
  bf16x8_t v3 = *(const bf16x8_t*)(p + 29 * CH);
  bf16x8_t ov;
#pragma unroll
  for (int j = 0; j < 8; ++j) {
    float m = bf2f((u16)v0[j]);
    m = fmaxf(m, bf2f((u16)v1[j]));
    m = fmaxf(m, bf2f((u16)v2[j]));
    m = fmaxf(m, bf2f((u16)v3[j]));
    ov[j] = (short)f2bf(m);
  }
  *(bf16x8_t*)(xpT + ((long long)(b * NK + nk)) * CH + c8 * 8) = ov;
}

// ---------------- generic bf16 GEMM  C[m,n] = (sum_k A[m,k]*B[n,k] + bias)*scale ----
// m97 structure: 256 thr / 4 waves, BMxBN tile, BK=64, global_load_lds width 16.
template<int BM, int BN, int BIAS_M, int OUT_BF16>
__global__ __launch_bounds__(256) void k_gemm_bt(
    const u16* __restrict__ A, const u16* __restrict__ B,
    void* __restrict__ Cout, const float* __restrict__ bias,
    int M, int N, int K, float scale,
    long long sA, long long sB, long long sC)
{
  __shared__ __align__(16) u16 As[BM * 64];
  __shared__ __align__(16) u16 Bs[BN * 64];
  const int z = blockIdx.z;
  A += (long long)z * sA; B += (long long)z * sB;
  const int tid = threadIdx.x, wave = tid >> 6, lane = tid & 63;
  const int l15 = lane & 15, l4 = lane >> 4;
  const int m0 = blockIdx.y * BM, n0 = blockIdx.x * BN;
  constexpr int WM = BM / 2, WN = BN / 2, FM = WM / 16, FN = WN / 16;
  const int wm = (wave >> 1) * WM, wn = (wave & 1) * WN;
  f32x4_t acc[FM][FN] = {};
  const int srow = lane >> 3, schunk = lane & 7;
  constexpr int RA = BM / 4, RB = BN / 4;
  for (int kt = 0; kt < K; kt += 64) {
#pragma unroll
    for (int i = 0; i < RA / 8; ++i) {
      int r = wave * RA + i * 8;
      GLDS16(A + (long long)(m0 + r + srow) * K + kt + schunk * 8, &As[r * 64]);
    }
#pragma unroll
    for (int i = 0; i < RB / 8; ++i) {
      int r = wave * RB + i * 8;
      GLDS16(B + (long long)(n0 + r + srow) * K + kt + schunk * 8, &Bs[r * 64]);
    }
    __syncthreads();
#pragma unroll
    for (int kk = 0; kk < 64; kk += 32) {
      bf16x8_t af[FM], bfv[FN];
#pragma unroll
      for (int i = 0; i < FM; ++i)
        af[i] = *(const bf16x8_t*)&As[(wm + i * 16 + l15) * 64 + kk + l4 * 8];
#pragma unroll
      for (int j = 0; j < FN; ++j)
        bfv[j] = *(const bf16x8_t*)&Bs[(wn + j * 16 + l15) * 64 + kk + l4 * 8];
#pragma unroll
      for (int i = 0; i < FM; ++i)
#pragma unroll
        for (int j = 0; j < FN; ++j)
          acc[i][j] = MFMA16(af[i], bfv[j], acc[i][j]);
    }
    __syncthreads();
  }
#pragma unroll
  for (int i = 0; i < FM; ++i) {
#pragma unroll
    for (int j = 0; j < FN; ++j) {
#pragma unroll
      for (int r = 0; r < 4; ++r) {
        int row = m0 + wm + i * 16 + l4 * 4 + r;
        int col = n0 + wn + j * 16 + l15;
        float v = (acc[i][j][r] + (BIAS_M ? bias[row] : bias[col])) * scale;
        if (OUT_BF16)
          ((u16*)Cout)[(long long)z * sC + (long long)row * N + col] = f2bf(v);
        else
          ((float*)Cout)[(long long)z * sC + (long long)row * N + col] = v;
      }
    }
  }
}

// ---------------- fused attention: Y = softmax(Q K^T) * G^T ----------------
// Q:(B*N,512) Km:(B*Nk,512) Gc:(B,512,Nk) -> Y:(B*N,512), no max-subtraction.
__global__ __launch_bounds__(512) void k_attn(
    const u16* __restrict__ Q, const u16* __restrict__ Km,
    const u16* __restrict__ Gc, u16* __restrict__ Y)
{
  __shared__ __align__(16) u16 Ks[64 * 520];   // K tile, padded rows (520)
  __shared__ __align__(16) u16 P[64 * 72];     // exp(S) tile, padded rows (72)
  __shared__ float RS[2][64];
  const int b = blockIdx.y;
  const int q0 = blockIdx.x * 64;
  const int tid = threadIdx.x, wave = tid >> 6, lane = tid & 63;
  const int l15 = lane & 15, l4 = lane >> 4;
  const int wr = wave >> 1, wk = wave & 1, dw = wave * 64;
  const u16* Qb = Q + (long long)b * NSP * CI_;
  const u16* Kb = Km + (long long)b * NK * CI_;
  const u16* Gb = Gc + (long long)b * CI_ * NK;
  u16* Yb = Y + (long long)b * NSP * CI_;

  bf16x8_t qf[16];
  {
    const u16* qp = Qb + (long long)(q0 + wr * 16 + l15) * CI_ + l4 * 8;
#pragma unroll
    for (int kf = 0; kf < 16; ++kf) qf[kf] = *(const bf16x8_t*)(qp + kf * 32);
  }
  f32x4_t o[4][4] = {};
  float rs[4] = {0.f, 0.f, 0.f, 0.f};

  for (int it = 0; it < 49; ++it) {
    const int nk0 = it * 64;
    {
      int r = tid >> 3, c0 = tid & 7;
      const u16* src = Kb + (long long)(nk0 + r) * CI_ + c0 * 8;
      u16* dst = &Ks[r * 520 + c0 * 8];
#pragma unroll
      for (int i = 0; i < 8; ++i)
        *(int4*)(dst + i * 64) = *(const int4*)(src + i * 64);
    }
    __syncthreads();
    // phase 1: S = Q K^T for this wave's 16 q-rows x 32 keys; exp -> P
#pragma unroll
    for (int nf = 0; nf < 2; ++nf) {
      f32x4_t s = {0.f, 0.f, 0.f, 0.f};
      const u16* krow = &Ks[(wk * 32 + nf * 16 + l15) * 520 + l4 * 8];
#pragma unroll
      for (int kf = 0; kf < 16; ++kf) {
        bf16x8_t kf8 = *(const bf16x8_t*)(krow + kf * 32);
        s = MFMA16(qf[kf], kf8, s);
      }
#pragma unroll
      for (int r = 0; r < 4; ++r) {
        float p = __expf(s[r]);
        rs[r] += p;
        P[(wr * 16 + l4 * 4 + r) * 72 + wk * 32 + nf * 16 + l15] = f2bf(p);
      }
    }
    __syncthreads();
    // phase 2: O += P * G  (this wave's 64 d-columns)
#pragma unroll
    for (int kf2 = 0; kf2 < 2; ++kf2) {
      bf16x8_t af[4];
#pragma unroll
      for (int mq = 0; mq < 4; ++mq)
        af[mq] = *(const bf16x8_t*)&P[(mq * 16 + l15) * 72 + kf2 * 32 + l4 * 8];
#pragma unroll
      for (int nd = 0; nd < 4; ++nd) {
        bf16x8_t gv = *(const bf16x8_t*)(Gb + (long long)(dw + nd * 16 + l15) * NK + nk0 + kf2 * 32 + l4 * 8);
#pragma unroll
        for (int mq = 0; mq < 4; ++mq)
          o[mq][nd] = MFMA16(af[mq], gv, o[mq][nd]);
      }
    }
  }
  // rowsum reduce across the 16 lanes sharing each row group
#pragma unroll
  for (int r = 0; r < 4; ++r) {
    float v = rs[r];
    v += __shfl_xor(v, 1); v += __shfl_xor(v, 2);
    v += __shfl_xor(v, 4); v += __shfl_xor(v, 8);
    rs[r] = v;
  }
  if (l15 == 0) {
#pragma unroll
    for (int r = 0; r < 4; ++r) RS[wk][wr * 16 + l4 * 4 + r] = rs[r];
  }
  __syncthreads();
#pragma unroll
  for (int mq = 0; mq < 4; ++mq) {
#pragma unroll
    for (int r = 0; r < 4; ++r) {
      int rl = mq * 16 + l4 * 4 + r;
      float inv = 1.0f / (RS[0][rl] + RS[1][rl]);
#pragma unroll
      for (int nd = 0; nd < 4; ++nd)
        Yb[(long long)(q0 + rl) * CI_ + dw + nd * 16 + l15] = f2bf(o[mq][nd][r] * inv);
    }
  }
}

// ---------------- BN stats: per-channel mean & rsqrt(var+eps) over (B,N) -------
__global__ __launch_bounds__(256) void k_bnstats(
    const float* __restrict__ wy, float* __restrict__ stat)
{
  __shared__ double sd[256], sq[256];
  int c = blockIdx.x, tid = threadIdx.x;
  double s = 0.0, s2 = 0.0;
  for (int b = 0; b < 4; ++b) {
    const float4* p = (const float4*)(wy + ((long long)b * CH + c) * NSP);
    for (int i = tid; i < NSP / 4; i += 256) {
      float4 v = p[i];
      s += (double)v.x + (double)v.y + (double)v.z + (double)v.w;
      s2 += (double)v.x * v.x + (double)v.y * v.y + (double)v.z * v.z + (double)v.w * v.w;
    }
  }
  sd[tid] = s; sq[tid] = s2;
  __syncthreads();
  for (int k = 128; k > 0; k >>= 1) {
    if (tid < k) { sd[tid] += sd[tid + k]; sq[tid] += sq[tid + k]; }
    __syncthreads();
  }
  if (tid == 0) {
    double mean = sd[0] / (4.0 * NSP);
    double var = sq[0] / (4.0 * NSP) - mean * mean;
    stat[c] = (float)mean;
    stat[CH + c] = (float)(1.0 / sqrt(var + 1e-5));
  }
}

// ---------------- finalize: out = (wy-mean)*inv*gamma + beta + x ----------------
__global__ __launch_bounds__(256) void k_final(
    float* __restrict__ out, const float* __restrict__ x,
    const float* __restrict__ stat, const float* __restrict__ gamma,
    const float* __restrict__ beta)
{
  const long long total = (long long)NB * CH * NSP / 4;
  for (long long i = blockIdx.x * 256 + threadIdx.x; i < total; i += (long long)gridDim.x * 256) {
    long long e = i * 4;
    int c = (int)((e / NSP) & (CH - 1));
    float a = gamma[c] * stat[CH + c];
    float bb = beta[c] - stat[c] * a;
    float4 w = ((const float4*)out)[i];
    float4 xv = ((const float4*)x)[i];
    float4 rv;
    rv.x = w.x * a + bb + xv.x;
    rv.y = w.y * a + bb + xv.y;
    rv.z = w.z * a + bb + xv.z;
    rv.w = w.w * a + bb + xv.w;
    ((float4*)out)[i] = rv;
  }
}

__global__ void k_sentinel(float* out) { out[0] = -12345.0f; }

extern "C" void kernel_launch(void* const* d_in, const int* in_sizes, int n_in,
                              void* d_out, int out_size, void* d_ws, size_t ws_size,
                              hipStream_t stream)
{
  const float* x       = (const float*)d_in[0];
  const float* theta_w = (const float*)d_in[1];
  const float* theta_b = (const float*)d_in[2];
  const float* phi_w   = (const float*)d_in[3];
  const float* phi_b   = (const float*)d_in[4];
  const float* g_w     = (const float*)d_in[5];
  const float* g_b     = (const float*)d_in[6];
  const float* w_w     = (const float*)d_in[7];
  const float* w_b     = (const float*)d_in[8];
  const float* bn_g    = (const float*)d_in[9];
  const float* bn_b    = (const float*)d_in[10];
  float* out = (float*)d_out;

  char* ws = (char*)d_ws;
  u16* xT   = (u16*)(ws);                      // (B,N,C)  bf16  102,760,448 B
  u16* xpT  = (u16*)(ws + 102760448);          // (B,Nk,C) bf16   25,690,112
  u16* Qm   = (u16*)(ws + 128450560);          // (B*N,512)       51,380,224
  u16* Kmm  = (u16*)(ws + 179830784);          // (B*Nk,512)      12,845,056
  u16* Gcc  = (u16*)(ws + 192675840);          // (B,512,Nk)      12,845,056
  u16* Ym   = (u16*)(ws + 205520896);          // (B*N,512)       51,380,224
  u16* Wbf  = (u16*)(ws + 256901120);          // 4 weights bf16   4,194,304
  float* stat = (float*)(ws + 261095424);      // mean/inv         8,192
  if (ws_size < 261103616ull) { k_sentinel<<<1, 1, 0, stream>>>(out); return; }

  u16* tw = Wbf;
  u16* pw = Wbf + 524288;
  u16* gw = Wbf + 1048576;
  u16* ww = Wbf + 1572864;

  k_cast_w<<<8192, 256, 0, stream>>>(theta_w, phi_w, g_w, w_w, Wbf);
  k_transpose<<<dim3(196, 16, 4), 256, 0, stream>>>(x, xT);
  k_pool<<<6272, 256, 0, stream>>>(xT, xpT);

  const float qscale = 0.044194173824159216f;  // 512^-0.5
  // Q = xT . theta_w^T  (+theta_b)*scale        M=50176 N=512 K=1024
  k_gemm_bt<128, 128, 0, 1><<<dim3(4, 392, 1), 256, 0, stream>>>(
      xT, tw, Qm, theta_b, 50176, 512, 1024, qscale, 0, 0, 0);
  // K = xpT . phi_w^T (+phi_b)                  M=12544 N=512 K=1024
  k_gemm_bt<128, 128, 0, 1><<<dim3(4, 98, 1), 256, 0, stream>>>(
      xpT, pw, Kmm, phi_b, 12544, 512, 1024, 1.0f, 0, 0, 0);
  // Gc = g_w . xpT_b^T (+g_b per row)           M=512 N=3136 K=1024, per batch
  k_gemm_bt<128, 64, 1, 1><<<dim3(49, 4, 4), 256, 0, stream>>>(
      gw, xpT, Gcc, g_b, 512, 3136, 1024, 1.0f,
      0, (long long)3136 * 1024, (long long)512 * 3136);
  // attention
  k_attn<<<dim3(196, 4), 512, 0, stream>>>(Qm, Kmm, Gcc, Ym);
  // wy = w_w . y^T (+w_b per row) -> d_out      M=1024 N=12544 K=512, per batch
  k_gemm_bt<128, 128, 1, 0><<<dim3(98, 8, 4), 256, 0, stream>>>(
      ww, Ym, out, w_b, 1024, 12544, 512, 1.0f,
      0, (long long)12544 * 512, (long long)1024 * 12544);

  k_bnstats<<<1024, 256, 0, stream>>>(out, stat);
  k_final<<<4096, 256, 0, stream>>>(out, x, stat, bn_g, bn_b);
}